// Round 1
// baseline (264.292 us; speedup 1.0000x reference)
//
#include <hip/hip_runtime.h>
#include <hip/hip_bf16.h>
#include <stdint.h>

// Problem constants (SpatialDecoder: B=128, N=1024, DM=64, S=2, D_IN=68)
#define NB 128
#define NN 1024
#define NDM 64

typedef __bf16 bf16;
typedef __bf16 bf16x8_t __attribute__((ext_vector_type(8)));
typedef __bf16 bf16x4_t __attribute__((ext_vector_type(4)));
typedef float f32x4 __attribute__((ext_vector_type(4)));

// ---------------------------------------------------------------------------
// k0: fold W_gc @ W_in -> Wy [128 x 68], and bias by[so] = W_gc_s @ b_in
// ---------------------------------------------------------------------------
__global__ __launch_bounds__(256) void k_prep_w(
    const float* __restrict__ W_in, const float* __restrict__ b_in,
    const float* __restrict__ W_gc, float* __restrict__ Wy, float* __restrict__ by) {
  int i = blockIdx.x * 256 + threadIdx.x;
  if (i < 128 * 68) {
    int so = i / 68, cp = i % 68;
    int s = so >> 6, o = so & 63;
    float acc = 0.f;
    for (int c = 0; c < 64; ++c) acc += W_gc[o * 128 + s * 64 + c] * W_in[c * 68 + cp];
    Wy[i] = acc;
  } else if (i < 128 * 68 + 128) {
    int so = i - 128 * 68;
    int s = so >> 6, o = so & 63;
    float acc = 0.f;
    for (int c = 0; c < 64; ++c) acc += W_gc[o * 128 + s * 64 + c] * b_in[c];
    by[so] = acc;
  }
}

// ---------------------------------------------------------------------------
// k2: adj f32 -> bf16 (2M elements), float4-vectorized
// ---------------------------------------------------------------------------
__global__ __launch_bounds__(256) void k_adj_bf16(
    const float* __restrict__ adj, bf16* __restrict__ adjb) {
  int i = blockIdx.x * 256 + threadIdx.x;  // one float4 per thread
  float4 v = reinterpret_cast<const float4*>(adj)[i];
  bf16x4_t r;
  r.x = (bf16)v.x; r.y = (bf16)v.y; r.z = (bf16)v.z; r.w = (bf16)v.w;
  reinterpret_cast<bf16x4_t*>(adjb)[i] = r;
}

// ---------------------------------------------------------------------------
// k1: Y[b, o, s, v] = by[so] + sum_{c'<68} Wy[so,c'] * inp[b,c',v]  (bf16 out)
// Y layout: row (b*64+o), col (s*1024+v)  -> [8192 x 2048] bf16
// Block: 256 thr; wave og=t/64 owns 16 o's; lane owns 4 consecutive v.
// Grid: (N/256, S, B)
// ---------------------------------------------------------------------------
__global__ __launch_bounds__(256) void k_build_y(
    const float* __restrict__ x, const float* __restrict__ m, const float* __restrict__ u,
    const float* __restrict__ h, const float* __restrict__ Wy, const float* __restrict__ by,
    bf16* __restrict__ Y) {
  __shared__ __align__(16) float Wt[68 * 64];  // transposed: Wt[c'][o]
  __shared__ float bl[64];
  const int t = threadIdx.x;
  const int s = blockIdx.y, b = blockIdx.z;
  for (int i = t; i < 68 * 64; i += 256) {
    int cp = i >> 6, o = i & 63;
    Wt[i] = Wy[(s * 64 + o) * 68 + cp];
  }
  if (t < 64) bl[t] = by[s * 64 + t];
  __syncthreads();
  const int og = t >> 6, lane = t & 63;
  const int vb = blockIdx.x * 256;

  float acc[16][4];
#pragma unroll
  for (int oi = 0; oi < 16; ++oi) {
    float bv = bl[og * 16 + oi];
    acc[oi][0] = bv; acc[oi][1] = bv; acc[oi][2] = bv; acc[oi][3] = bv;
  }

  auto doCh = [&](int cp, const float* base) {
    float4 v = *reinterpret_cast<const float4*>(base + lane * 4);
    const float4* wr = reinterpret_cast<const float4*>(&Wt[cp * 64 + og * 16]);
    float wv[16];
    *reinterpret_cast<float4*>(&wv[0])  = wr[0];
    *reinterpret_cast<float4*>(&wv[4])  = wr[1];
    *reinterpret_cast<float4*>(&wv[8])  = wr[2];
    *reinterpret_cast<float4*>(&wv[12]) = wr[3];
#pragma unroll
    for (int oi = 0; oi < 16; ++oi) {
      acc[oi][0] += wv[oi] * v.x;
      acc[oi][1] += wv[oi] * v.y;
      acc[oi][2] += wv[oi] * v.z;
      acc[oi][3] += wv[oi] * v.w;
    }
  };

  doCh(0, x + b * NN + vb);
  doCh(1, m + b * NN + vb);
  doCh(2, u + (b * 2 + 0) * NN + vb);
  doCh(3, u + (b * 2 + 1) * NN + vb);
  for (int c = 0; c < 64; ++c) doCh(4 + c, h + ((size_t)(b * 64 + c)) * NN + vb);

#pragma unroll
  for (int oi = 0; oi < 16; ++oi) {
    bf16x4_t r;
    r.x = (bf16)acc[oi][0]; r.y = (bf16)acc[oi][1];
    r.z = (bf16)acc[oi][2]; r.w = (bf16)acc[oi][3];
    size_t row = (size_t)(b * 64 + og * 16 + oi);
    *reinterpret_cast<bf16x4_t*>(&Y[row * 2048 + s * 1024 + vb + lane * 4]) = r;
  }
}

// ---------------------------------------------------------------------------
// k3: GEMM  gc[(b,o), w] = b_gc[o] + sum_{k<2048} Y[(b,o),k] * ADJB[w, k]
// ADJB[w, s*1024+v] = adjb[s][w][v]  (B^T layout, row-major [w][v] per s)
// m97 structure: 128x128 tile, BK=32, 256 thr (4 waves, 2x2 of 64x64),
// global_load_lds width 16, 16x16x32 bf16 MFMA, 4x4 acc/wave. Output bf16.
// Grid: (M/128=64, N/128=8)
// ---------------------------------------------------------------------------
__global__ __launch_bounds__(256) void k_gemm(
    const bf16* __restrict__ Y, const bf16* __restrict__ ADJB,
    const float* __restrict__ b_gc, bf16* __restrict__ gc) {
  __shared__ __align__(16) bf16 As[128 * 32];
  __shared__ __align__(16) bf16 Bs[128 * 32];
  const int t = threadIdx.x;
  const int w = t >> 6, lane = t & 63;
  const int rowA = blockIdx.x * 128;
  const int colB = blockIdx.y * 128;
  const int wm = (w & 1) * 64, wn = (w >> 1) * 64;
  const int fr = lane & 15;         // fragment row (m / n)
  const int fk = (lane >> 4) * 8;   // fragment k offset

  f32x4 acc[4][4];
  const f32x4 zero = {0.f, 0.f, 0.f, 0.f};
#pragma unroll
  for (int i = 0; i < 4; ++i)
#pragma unroll
    for (int j = 0; j < 4; ++j) acc[i][j] = zero;

  const int c0 = w * 128 + lane;   // staging chunk (16B each), j=0
  const int c1 = c0 + 64;          // j=1

  for (int k0 = 0; k0 < 2048; k0 += 32) {
    const int s = k0 >> 10, v0 = k0 & 1023;
    // --- stage A tile (128 rows x 32 k, 8KB) ---
    {
      const bf16* g0 = Y + (size_t)(rowA + (c0 >> 2)) * 2048 + k0 + (c0 & 3) * 8;
      const bf16* g1 = Y + (size_t)(rowA + (c1 >> 2)) * 2048 + k0 + (c1 & 3) * 8;
      __builtin_amdgcn_global_load_lds((const uint32_t*)g0, (uint32_t*)&As[c0 * 8], 16, 0, 0);
      __builtin_amdgcn_global_load_lds((const uint32_t*)g1, (uint32_t*)&As[c1 * 8], 16, 0, 0);
      const bf16* bbase = ADJB + (size_t)s * (1024 * 1024) + v0;
      const bf16* gb0 = bbase + (size_t)(colB + (c0 >> 2)) * 1024 + (c0 & 3) * 8;
      const bf16* gb1 = bbase + (size_t)(colB + (c1 >> 2)) * 1024 + (c1 & 3) * 8;
      __builtin_amdgcn_global_load_lds((const uint32_t*)gb0, (uint32_t*)&Bs[c0 * 8], 16, 0, 0);
      __builtin_amdgcn_global_load_lds((const uint32_t*)gb1, (uint32_t*)&Bs[c1 * 8], 16, 0, 0);
    }
    __syncthreads();
    bf16x8_t af[4], bfr[4];
#pragma unroll
    for (int i = 0; i < 4; ++i)
      af[i] = *reinterpret_cast<const bf16x8_t*>(&As[(wm + i * 16 + fr) * 32 + fk]);
#pragma unroll
    for (int i = 0; i < 4; ++i)
      bfr[i] = *reinterpret_cast<const bf16x8_t*>(&Bs[(wn + i * 16 + fr) * 32 + fk]);
#pragma unroll
    for (int i = 0; i < 4; ++i)
#pragma unroll
      for (int j = 0; j < 4; ++j)
        acc[i][j] = __builtin_amdgcn_mfma_f32_16x16x32_bf16(af[i], bfr[j], acc[i][j], 0, 0, 0);
    __syncthreads();
  }

  // epilogue: C/D layout col=lane&15, row=(lane>>4)*4+r ; add b_gc, store bf16
#pragma unroll
  for (int i = 0; i < 4; ++i) {
#pragma unroll
    for (int r = 0; r < 4; ++r) {
      int gr = rowA + wm + i * 16 + (lane >> 4) * 4 + r;
      float bias = b_gc[gr & 63];
#pragma unroll
      for (int j = 0; j < 4; ++j) {
        int gcol = colB + wn + j * 16 + (lane & 15);
        gc[(size_t)gr * 1024 + gcol] = (bf16)(acc[i][j][r] + bias);
      }
    }
  }
}

// ---------------------------------------------------------------------------
// k4: fused epilogue.
//   out[b,o,n]  = PReLU(b_out[o] + sum_c W_out[o,c]*gc[b,c,n] + W_out[o,64+c]*h[b,c,n])
//   out2        = [out ; h]  (f32, h exact copy)
//   read[b,n]   = b_read + sum_o W_read[o]*out[b,o,n] + sum_c W_read[64+c]*h[b,c,n]
// Block: 256 thr; wave og owns 16 o's; lane owns 4 consecutive v. Grid: (N/256, B)
// ---------------------------------------------------------------------------
__global__ __launch_bounds__(256) void k_final(
    const bf16* __restrict__ gc, const float* __restrict__ h,
    const float* __restrict__ W_out, const float* __restrict__ b_out,
    const float* __restrict__ W_read, const float* __restrict__ b_read,
    const float* __restrict__ prelu_w, float* __restrict__ out0, float* __restrict__ out2) {
  __shared__ __align__(16) float Wt1[64 * 64];  // Wt1[c][o] = W_out[o, c]
  __shared__ __align__(16) float Wt2[64 * 64];  // Wt2[c][o] = W_out[o, 64+c]
  __shared__ float Wr[128];
  __shared__ float bo[64];
  __shared__ float red[4 * 256];
  const int t = threadIdx.x;
  for (int i = t; i < 4096; i += 256) {
    int c = i >> 6, o = i & 63;
    Wt1[i] = W_out[o * 128 + c];
    Wt2[i] = W_out[o * 128 + 64 + c];
  }
  if (t < 128) Wr[t] = W_read[t];
  if (t < 64) bo[t] = b_out[t];
  __syncthreads();
  const int og = t >> 6, lane = t & 63;
  const int vb = blockIdx.x * 256;
  const int b = blockIdx.y;

  float acc[16][4];
#pragma unroll
  for (int oi = 0; oi < 16; ++oi) {
    float bv = bo[og * 16 + oi];
    acc[oi][0] = bv; acc[oi][1] = bv; acc[oi][2] = bv; acc[oi][3] = bv;
  }
  float racc[4] = {0.f, 0.f, 0.f, 0.f};

  for (int c = 0; c < 64; ++c) {
    size_t base = (size_t)(b * 64 + c) * NN + vb + lane * 4;
    bf16x4_t gvb = *reinterpret_cast<const bf16x4_t*>(&gc[base]);
    float4 hv = *reinterpret_cast<const float4*>(&h[base]);
    float gv0 = (float)gvb.x, gv1 = (float)gvb.y, gv2 = (float)gvb.z, gv3 = (float)gvb.w;
    const float4* w1p = reinterpret_cast<const float4*>(&Wt1[c * 64 + og * 16]);
    const float4* w2p = reinterpret_cast<const float4*>(&Wt2[c * 64 + og * 16]);
    float w1[16], w2[16];
    *reinterpret_cast<float4*>(&w1[0])  = w1p[0];
    *reinterpret_cast<float4*>(&w1[4])  = w1p[1];
    *reinterpret_cast<float4*>(&w1[8])  = w1p[2];
    *reinterpret_cast<float4*>(&w1[12]) = w1p[3];
    *reinterpret_cast<float4*>(&w2[0])  = w2p[0];
    *reinterpret_cast<float4*>(&w2[4])  = w2p[1];
    *reinterpret_cast<float4*>(&w2[8])  = w2p[2];
    *reinterpret_cast<float4*>(&w2[12]) = w2p[3];
#pragma unroll
    for (int oi = 0; oi < 16; ++oi) {
      acc[oi][0] += w1[oi] * gv0 + w2[oi] * hv.x;
      acc[oi][1] += w1[oi] * gv1 + w2[oi] * hv.y;
      acc[oi][2] += w1[oi] * gv2 + w2[oi] * hv.z;
      acc[oi][3] += w1[oi] * gv3 + w2[oi] * hv.w;
    }
    if (og == 0) {  // h passthrough (exact) + read h-part
      *reinterpret_cast<float4*>(&out2[(size_t)(b * 128 + 64 + c) * NN + vb + lane * 4]) = hv;
      float wrh = Wr[64 + c];
      racc[0] += wrh * hv.x; racc[1] += wrh * hv.y;
      racc[2] += wrh * hv.z; racc[3] += wrh * hv.w;
    }
  }

  const float pw = prelu_w[0];
#pragma unroll
  for (int oi = 0; oi < 16; ++oi) {
    float wro = Wr[og * 16 + oi];
    float4 st;
    float q0 = acc[oi][0]; q0 = q0 >= 0.f ? q0 : pw * q0;
    float q1 = acc[oi][1]; q1 = q1 >= 0.f ? q1 : pw * q1;
    float q2 = acc[oi][2]; q2 = q2 >= 0.f ? q2 : pw * q2;
    float q3 = acc[oi][3]; q3 = q3 >= 0.f ? q3 : pw * q3;
    st.x = q0; st.y = q1; st.z = q2; st.w = q3;
    *reinterpret_cast<float4*>(&out2[(size_t)(b * 128 + og * 16 + oi) * NN + vb + lane * 4]) = st;
    racc[0] += wro * q0; racc[1] += wro * q1; racc[2] += wro * q2; racc[3] += wro * q3;
  }

#pragma unroll
  for (int j = 0; j < 4; ++j) red[og * 256 + lane * 4 + j] = racc[j];
  __syncthreads();
  if (og == 0) {
    float br = b_read[0];
    float4 st;
    int vi = lane * 4;
    st.x = red[vi + 0] + red[256 + vi + 0] + red[512 + vi + 0] + red[768 + vi + 0] + br;
    st.y = red[vi + 1] + red[256 + vi + 1] + red[512 + vi + 1] + red[768 + vi + 1] + br;
    st.z = red[vi + 2] + red[256 + vi + 2] + red[512 + vi + 2] + red[768 + vi + 2] + br;
    st.w = red[vi + 3] + red[256 + vi + 3] + red[512 + vi + 3] + red[768 + vi + 3] + br;
    *reinterpret_cast<float4*>(&out0[(size_t)b * NN + vb + vi]) = st;
  }
}

// ---------------------------------------------------------------------------
extern "C" void kernel_launch(void* const* d_in, const int* in_sizes, int n_in,
                              void* d_out, int out_size, void* d_ws, size_t ws_size,
                              hipStream_t stream) {
  (void)in_sizes; (void)n_in; (void)out_size; (void)ws_size;
  const float* x       = (const float*)d_in[0];
  const float* m       = (const float*)d_in[1];
  const float* u       = (const float*)d_in[2];
  const float* h       = (const float*)d_in[3];
  const float* adj     = (const float*)d_in[4];
  const float* W_in    = (const float*)d_in[5];
  const float* b_in    = (const float*)d_in[6];
  const float* W_gc    = (const float*)d_in[7];
  const float* b_gc    = (const float*)d_in[8];
  const float* W_out   = (const float*)d_in[9];
  const float* b_out   = (const float*)d_in[10];
  const float* W_read  = (const float*)d_in[11];
  const float* b_read  = (const float*)d_in[12];
  const float* prelu_w = (const float*)d_in[13];

  char* ws = (char*)d_ws;
  bf16*  Y    = (bf16*)(ws);                       // 8192*2048*2  = 33554432 B
  bf16*  ADJB = (bf16*)(ws + 33554432);            // 2*1024*1024*2 = 4194304 B
  bf16*  GC   = (bf16*)(ws + 37748736);            // 8192*1024*2  = 16777216 B
  float* WY   = (float*)(ws + 54525952);           // 128*68*4     = 34816 B
  float* BY   = (float*)(ws + 54560768);           // 128*4        = 512 B

  float* out0 = (float*)d_out;           // read  [B,1,N]  = 131072
  float* out2 = out0 + 131072;           // out2  [B,128,N]

  hipLaunchKernelGGL(k_prep_w,  dim3(35),         dim3(256), 0, stream, W_in, b_in, W_gc, WY, BY);
  hipLaunchKernelGGL(k_adj_bf16,dim3(2048),       dim3(256), 0, stream, adj, ADJB);
  hipLaunchKernelGGL(k_build_y, dim3(4, 2, 128),  dim3(256), 0, stream, x, m, u, h, WY, BY, Y);
  hipLaunchKernelGGL(k_gemm,    dim3(64, 8),      dim3(256), 0, stream, Y, ADJB, b_gc, GC);
  hipLaunchKernelGGL(k_final,   dim3(4, 128),     dim3(256), 0, stream, GC, h, W_out, b_out, W_read, b_read, prelu_w, out0, out2);
}